// Round 6
// baseline (2323.489 us; speedup 1.0000x reference)
//
#include <hip/hip_runtime.h>
#include <math.h>

#define BB 128
#define TT 1024
#define DD 128
#define HH 64
#define G3 192   // 3*H
#define KK 32

// ---------------------------------------------------------------------------
// Kernel 1: xproj[B*T,192] = X[B*T,128] @ Wk[128,192] + b0
// ---------------------------------------------------------------------------
__global__ __launch_bounds__(256, 2) void xproj_kernel(const float* __restrict__ X,
                                                       const float* __restrict__ Wk,
                                                       const float* __restrict__ gbias,
                                                       float* __restrict__ xp) {
    __shared__ float Xs[64 * 132];             // 64 rows x 128 k, stride 132 (pad)
    __shared__ float Ws[128 * 68];             // 128 k x 64 cols, stride 68 (pad)
    const int tid = threadIdx.x;
    const int row0 = blockIdx.x * 64;
    const int cg = blockIdx.y;                 // col group 0..2
#pragma unroll
    for (int it = 0; it < 8; ++it) {
        int idx = it * 1024 + tid * 4;
        int r = idx >> 7, c = idx & 127;
        float4 v = *(const float4*)&X[((size_t)(row0 + r)) * DD + c];
        *(float4*)&Xs[r * 132 + c] = v;
    }
#pragma unroll
    for (int it = 0; it < 8; ++it) {
        int idx = it * 1024 + tid * 4;
        int k = idx >> 6, c = idx & 63;
        float4 v = *(const float4*)&Wk[(size_t)k * G3 + cg * 64 + c];
        *(float4*)&Ws[k * 68 + c] = v;
    }
    __syncthreads();
    const int tr = tid >> 4, tc = tid & 15;    // 16x16 thread grid
    const int r0 = tr * 4, c0 = tc * 4;
    float acc[4][4];
#pragma unroll
    for (int r = 0; r < 4; ++r)
#pragma unroll
        for (int c = 0; c < 4; ++c) acc[r][c] = 0.f;
#pragma unroll 4
    for (int k = 0; k < DD; k += 4) {
        float a[4][4];
#pragma unroll
        for (int r = 0; r < 4; ++r) {
            float4 t = *(const float4*)&Xs[(r0 + r) * 132 + k];
            a[r][0] = t.x; a[r][1] = t.y; a[r][2] = t.z; a[r][3] = t.w;
        }
#pragma unroll
        for (int kk = 0; kk < 4; ++kk) {
            float4 b = *(const float4*)&Ws[(k + kk) * 68 + c0];
#pragma unroll
            for (int r = 0; r < 4; ++r) {
                acc[r][0] += a[r][kk] * b.x;
                acc[r][1] += a[r][kk] * b.y;
                acc[r][2] += a[r][kk] * b.z;
                acc[r][3] += a[r][kk] * b.w;
            }
        }
    }
    float4 bias = *(const float4*)&gbias[cg * 64 + c0];
#pragma unroll
    for (int r = 0; r < 4; ++r) {
        float4 o;
        o.x = acc[r][0] + bias.x; o.y = acc[r][1] + bias.y;
        o.z = acc[r][2] + bias.z; o.w = acc[r][3] + bias.w;
        *(float4*)&xp[((size_t)(row0 + r0 + r)) * G3 + cg * 64 + c0] = o;
    }
}

// ---------------------------------------------------------------------------
// Kernel 2: seq_len + chain copy
// ---------------------------------------------------------------------------
__global__ __launch_bounds__(256) void seqlen_kernel(const int* __restrict__ mask,
                                                     const float* __restrict__ chain,
                                                     float* __restrict__ out_seqlen,
                                                     float* __restrict__ out_chain,
                                                     int* __restrict__ ws_seqlen) {
    const int b = blockIdx.x;
    const int tid = threadIdx.x;
    int s = 0;
    for (int t = tid; t < TT; t += 256) s += mask[b * TT + t];
#pragma unroll
    for (int off = 32; off >= 1; off >>= 1) s += __shfl_down(s, off, 64);
    __shared__ int red[4];
    if ((tid & 63) == 0) red[tid >> 6] = s;
    __syncthreads();
    if (tid == 0) {
        int tot = red[0] + red[1] + red[2] + red[3];
        out_seqlen[b] = (float)tot;
        ws_seqlen[b] = tot;
    }
    if (b == 0) {
        for (int i = tid; i < KK * KK; i += 256) out_chain[i] = chain[i];
    }
}

// ---------------------------------------------------------------------------
// Kernel 3: GRU scan — 6-wave split: wave w = (gate g=w>>1, half hf=w&1).
// Lane j of wave w holds Wr[hf*32 .. hf*32+31][g*64+j] (32 VGPRs). Per step
// each wave does a 32-long readlane+fmac partial matvec (half of R5's 64),
// writes the RAW partial sum to LDS, barriers ONCE, then every wave
// redundantly computes the full gate math + h update (gate math is off the
// pre-barrier critical path). Double-buffered partials; no spill possible.
// ---------------------------------------------------------------------------
#define BCAST(v, l) __int_as_float(__builtin_amdgcn_readlane(__float_as_int(v), (l)))

__global__ __launch_bounds__(384)
void gru_kernel(const float* __restrict__ xp,
                const float* __restrict__ Wr,
                const float* __restrict__ gbias,
                const int* __restrict__ mask,
                float* __restrict__ hidden) {
    const int b = blockIdx.x;
    const int tid = threadIdx.x;
    const int w = tid >> 6;                    // 0..5
    const int j = tid & 63;
    const int g = w >> 1;                      // gate: 0=z, 1=r, 2=h-cand
    const int hf = w & 1;                      // summand half
    __shared__ float part[2][6][HH];           // raw partial sums, double-buffered
    float wg[32];
#define LWG(i)  wg[(i)] = Wr[(hf * 32 + (i)) * G3 + g * HH + j];
#define LWG4(i)  LWG(i) LWG((i)+1) LWG((i)+2) LWG((i)+3)
#define LWG16(i) LWG4(i) LWG4((i)+4) LWG4((i)+8) LWG4((i)+12)
    LWG16(0) LWG16(16)
    const float bw = hf ? 0.f : gbias[G3 + g * HH + j];  // recurrent bias once
    float h = 0.f;                             // lane j holds h_j (per-wave copy)
    const float* xpb = xp + (size_t)b * TT * G3;
    const int bTT = b * TT;
    float xz = xpb[j], xr = xpb[HH + j], xh = xpb[2 * HH + j];
    int m = mask[bTT];
    const int base = hf * 32;                  // wave-uniform readlane base
    for (int t = 0; t < TT; ++t) {
        const int tn = (t + 1 < TT) ? t + 1 : TT - 1;
        const float* xn = xpb + (size_t)tn * G3;
        float nxz = xn[j], nxr = xn[HH + j], nxh = xn[2 * HH + j];
        int nm = mask[bTT + tn];
        // 32-summand partial matvec, 4 accumulator chains
        float a0 = bw, a1 = 0.f, a2 = 0.f, a3 = 0.f;
#define GST(i, A) { float hi_ = BCAST(h, base + (i)); A += hi_ * wg[(i)]; }
#define GST4(i)  GST(i, a0) GST((i)+1, a1) GST((i)+2, a2) GST((i)+3, a3)
#define GST16(i) GST4(i) GST4((i)+4) GST4((i)+8) GST4((i)+12)
        GST16(0) GST16(16)
        const int p = t & 1;
        part[p][w][j] = (a0 + a1) + (a2 + a3);
        __syncthreads();
        float az = part[p][0][j] + part[p][1][j];
        float ar = part[p][2][j] + part[p][3][j];
        float ah = part[p][4][j] + part[p][5][j];
        float z = 1.f / (1.f + __expf(-(xz + az)));
        float r = 1.f / (1.f + __expf(-(xr + ar)));
        float y = xh + r * ah;
        float hh = 1.f - 2.f / (1.f + __expf(2.f * y));   // tanh(y)
        float hn = z * h + (1.f - z) * hh;
        hn = (m != 0) ? hn : h;
        if (w == 0) hidden[((size_t)(bTT + t)) * HH + j] = hn;
        h = hn;
        xz = nxz; xr = nxr; xh = nxh; m = nm;
    }
}

// ---------------------------------------------------------------------------
// Kernel 4: potentials[row,k] = hidden[row,:]@Dk[:,k] + db[k] (+ boundaries)
// ---------------------------------------------------------------------------
#define PR 8
__global__ __launch_bounds__(256) void pot_kernel(const float* __restrict__ hidden,
                                                  const float* __restrict__ Dk,
                                                  const float* __restrict__ db,
                                                  const float* __restrict__ lb,
                                                  const float* __restrict__ rb,
                                                  const int* __restrict__ slen,
                                                  float* __restrict__ pot) {
    __shared__ float Hs[PR * HH];
    __shared__ float Dks[HH * KK];
    const int tid = threadIdx.x;
    const int k = tid & (KK - 1);
    const int rl = tid >> 5;                   // 0..7
    const size_t row0 = (size_t)blockIdx.x * PR;
    for (int idx = tid; idx < PR * HH; idx += 256) Hs[idx] = hidden[row0 * HH + idx];
    for (int idx = tid; idx < HH * KK; idx += 256) Dks[idx] = Dk[idx];
    __syncthreads();
    float acc = db[k];
#pragma unroll
    for (int i = 0; i < HH; i += 4) {
        float4 hv = *(const float4*)&Hs[rl * HH + i];
        acc += hv.x * Dks[i * KK + k] + hv.y * Dks[(i + 1) * KK + k]
             + hv.z * Dks[(i + 2) * KK + k] + hv.w * Dks[(i + 3) * KK + k];
    }
    const size_t row = row0 + rl;
    const int t = (int)(row & (TT - 1));
    const int bb = (int)(row >> 10);
    if (t == 0) acc += lb[k];
    if (t == slen[bb] - 1) acc += rb[k];
    pot[row * KK + k] = acc;
}

// ---------------------------------------------------------------------------
// Kernel 5: Viterbi. Column layout: lane k computes ALL 32 k_from candidates
// (32 bpermutes + one 5-level first-index argmax tree) — removes the second
// 120-cyc cross-half bpermute hop of the old 2-half layout. Lanes 32..63
// mirror lanes 0..31 (same addresses -> same values; harmless).
// 4-deep pot-row prefetch; bp uint8 in LDS; chunked parallel backtrack.
// ---------------------------------------------------------------------------
__global__ __launch_bounds__(256) void viterbi_kernel(const float* __restrict__ pot,
                                                      const float* __restrict__ chain,
                                                      float* __restrict__ decoded) {
    const int b = blockIdx.x;
    const int tid = threadIdx.x;
    __shared__ unsigned char bp[(TT - 1) * KK];        // 32736 B
    __shared__ unsigned char table[32 * 32 * KK];      // 32 chunks x 32 pos x 32 cand
    __shared__ int ent[32];
    __shared__ int last_tag_s;
    const float* pb = pot + (size_t)b * TT * KK;

    if (tid < 64) {
        const int k = tid & 31;
        float ccol[32];
#pragma unroll
        for (int m = 0; m < 32; ++m) ccol[m] = chain[m * KK + k];
        float s = pb[k];
        // 4-deep prefetch ring (reads past pot for b=127 land in slen/chain
        // area of d_out: allocated, values unused)
        float pv0 = pb[1 * KK + k];
        float pv1 = pb[2 * KK + k];
        float pv2 = pb[3 * KK + k];
        float pv3 = pb[4 * KK + k];
        for (int t = 1; t < TT; ++t) {
            float pv = pv0;
            pv0 = pv1; pv1 = pv2; pv2 = pv3;
            pv3 = pb[(size_t)(t + 4) * KK + k];
            const int si = __float_as_int(s);
            float c[32];
#pragma unroll
            for (int m = 0; m < 32; ++m)
                c[m] = __int_as_float(__builtin_amdgcn_ds_bpermute(m * 4, si)) + ccol[m];
            // 5-level first-index argmax tree (strict > keeps lower index)
            float v1[16]; int i1[16];
#pragma unroll
            for (int p = 0; p < 16; ++p) {
                bool tk = c[2 * p + 1] > c[2 * p];
                v1[p] = tk ? c[2 * p + 1] : c[2 * p];
                i1[p] = 2 * p + (tk ? 1 : 0);
            }
            float v2[8]; int i2[8];
#pragma unroll
            for (int p = 0; p < 8; ++p) {
                bool tk = v1[2 * p + 1] > v1[2 * p];
                v2[p] = tk ? v1[2 * p + 1] : v1[2 * p];
                i2[p] = tk ? i1[2 * p + 1] : i1[2 * p];
            }
            float v3[4]; int i3[4];
#pragma unroll
            for (int p = 0; p < 4; ++p) {
                bool tk = v2[2 * p + 1] > v2[2 * p];
                v3[p] = tk ? v2[2 * p + 1] : v2[2 * p];
                i3[p] = tk ? i2[2 * p + 1] : i2[2 * p];
            }
            float v4[2]; int i4[2];
#pragma unroll
            for (int p = 0; p < 2; ++p) {
                bool tk = v3[2 * p + 1] > v3[2 * p];
                v4[p] = tk ? v3[2 * p + 1] : v3[2 * p];
                i4[p] = tk ? i3[2 * p + 1] : i3[2 * p];
            }
            bool tk = v4[1] > v4[0];
            float bv = tk ? v4[1] : v4[0];
            int bi = tk ? i4[1] : i4[0];
            if (tid < 32) bp[(t - 1) * KK + k] = (unsigned char)bi;
            s = bv + pv;
        }
        // first-index argmax over final scores (upper half mirrors lower)
        float bv = s; int bi = k;
#pragma unroll
        for (int d = 16; d >= 1; d >>= 1) {
            float ov = __shfl_xor(bv, d, 64);
            int   oi = __shfl_xor(bi, d, 64);
            bool take = (ov > bv) || (ov == bv && oi < bi);
            if (take) { bv = ov; bi = oi; }
        }
        if (tid == 0) last_tag_s = bi;
    }
    __syncthreads();
    {
        const int k = tid & 31;
        const int cs = tid >> 5;                       // 0..7
        for (int cc = 0; cc < 4; ++cc) {
            const int c = cs * 4 + cc;
            int tag = k;
            for (int l = 31; l >= 0; --l) {
                const int t = c * 32 + l;
                if (t < TT - 1) tag = bp[t * KK + tag];
                table[(c * 32 + l) * KK + k] = (unsigned char)tag;
            }
        }
    }
    __syncthreads();
    if (tid == 0) {
        int e = last_tag_s;
        ent[31] = e;
        for (int c = 30; c >= 0; --c) { e = table[(c + 1) * 32 * KK + e]; ent[c] = e; }
    }
    __syncthreads();
    for (int t = tid; t < TT; t += 256) {
        const int c = t >> 5, l = t & 31;
        decoded[(size_t)b * TT + t] = (float)table[(c * 32 + l) * KK + ent[c]];
    }
}

// ---------------------------------------------------------------------------
extern "C" void kernel_launch(void* const* d_in, const int* in_sizes, int n_in,
                              void* d_out, int out_size, void* d_ws, size_t ws_size,
                              hipStream_t stream) {
    const float* X     = (const float*)d_in[0];
    const int*   mask  = (const int*)d_in[1];
    const float* Wk    = (const float*)d_in[2];   // [128,192]
    const float* Wr    = (const float*)d_in[3];   // [64,192]
    const float* gb    = (const float*)d_in[4];   // [2,192]
    const float* Dk    = (const float*)d_in[5];   // [64,32]
    const float* db    = (const float*)d_in[6];   // [32]
    const float* chain = (const float*)d_in[7];   // [32,32]
    const float* lb    = (const float*)d_in[8];
    const float* rb    = (const float*)d_in[9];

    float* out = (float*)d_out;
    float* out_dec  = out;                                   // [B,T]
    float* out_pot  = out + (size_t)BB * TT;                 // [B,T,K]
    float* out_slen = out + (size_t)BB * TT + (size_t)BB * TT * KK;        // [B]
    float* out_chn  = out_slen + BB;                         // [K,K]

    float* ws = (float*)d_ws;
    float* xp     = ws;                                      // [B*T,192]
    float* hidden = ws + (size_t)BB * TT * G3;               // [B*T,64]
    int*   slen_i = (int*)(hidden + (size_t)BB * TT * HH);   // [B]

    xproj_kernel<<<dim3((BB * TT) / 64, 3), dim3(256), 0, stream>>>(X, Wk, gb, xp);
    seqlen_kernel<<<dim3(BB), dim3(256), 0, stream>>>(mask, chain, out_slen, out_chn, slen_i);
    gru_kernel<<<dim3(BB), dim3(384), 0, stream>>>(xp, Wr, gb, mask, hidden);
    pot_kernel<<<dim3((BB * TT) / PR), dim3(256), 0, stream>>>(hidden, Dk, db, lb, rb, slen_i, out_pot);
    viterbi_kernel<<<dim3(BB), dim3(256), 0, stream>>>(out_pot, chain, out_dec);
}

// Round 7
// 1428.214 us; speedup vs baseline: 1.6268x; 1.6268x over previous
//
#include <hip/hip_runtime.h>
#include <math.h>

#define BB 128
#define TT 1024
#define DD 128
#define HH 64
#define G3 192   // 3*H
#define KK 32

// ---------------------------------------------------------------------------
// Kernel 1: xproj[B*T,192] = X[B*T,128] @ Wk[128,192] + b0
// ---------------------------------------------------------------------------
__global__ __launch_bounds__(256, 2) void xproj_kernel(const float* __restrict__ X,
                                                       const float* __restrict__ Wk,
                                                       const float* __restrict__ gbias,
                                                       float* __restrict__ xp) {
    __shared__ float Xs[64 * 132];             // 64 rows x 128 k, stride 132 (pad)
    __shared__ float Ws[128 * 68];             // 128 k x 64 cols, stride 68 (pad)
    const int tid = threadIdx.x;
    const int row0 = blockIdx.x * 64;
    const int cg = blockIdx.y;                 // col group 0..2
#pragma unroll
    for (int it = 0; it < 8; ++it) {
        int idx = it * 1024 + tid * 4;
        int r = idx >> 7, c = idx & 127;
        float4 v = *(const float4*)&X[((size_t)(row0 + r)) * DD + c];
        *(float4*)&Xs[r * 132 + c] = v;
    }
#pragma unroll
    for (int it = 0; it < 8; ++it) {
        int idx = it * 1024 + tid * 4;
        int k = idx >> 6, c = idx & 63;
        float4 v = *(const float4*)&Wk[(size_t)k * G3 + cg * 64 + c];
        *(float4*)&Ws[k * 68 + c] = v;
    }
    __syncthreads();
    const int tr = tid >> 4, tc = tid & 15;    // 16x16 thread grid
    const int r0 = tr * 4, c0 = tc * 4;
    float acc[4][4];
#pragma unroll
    for (int r = 0; r < 4; ++r)
#pragma unroll
        for (int c = 0; c < 4; ++c) acc[r][c] = 0.f;
#pragma unroll 4
    for (int k = 0; k < DD; k += 4) {
        float a[4][4];
#pragma unroll
        for (int r = 0; r < 4; ++r) {
            float4 t = *(const float4*)&Xs[(r0 + r) * 132 + k];
            a[r][0] = t.x; a[r][1] = t.y; a[r][2] = t.z; a[r][3] = t.w;
        }
#pragma unroll
        for (int kk = 0; kk < 4; ++kk) {
            float4 b = *(const float4*)&Ws[(k + kk) * 68 + c0];
#pragma unroll
            for (int r = 0; r < 4; ++r) {
                acc[r][0] += a[r][kk] * b.x;
                acc[r][1] += a[r][kk] * b.y;
                acc[r][2] += a[r][kk] * b.z;
                acc[r][3] += a[r][kk] * b.w;
            }
        }
    }
    float4 bias = *(const float4*)&gbias[cg * 64 + c0];
#pragma unroll
    for (int r = 0; r < 4; ++r) {
        float4 o;
        o.x = acc[r][0] + bias.x; o.y = acc[r][1] + bias.y;
        o.z = acc[r][2] + bias.z; o.w = acc[r][3] + bias.w;
        *(float4*)&xp[((size_t)(row0 + r0 + r)) * G3 + cg * 64 + c0] = o;
    }
}

// ---------------------------------------------------------------------------
// Kernel 2: seq_len + chain copy
// ---------------------------------------------------------------------------
__global__ __launch_bounds__(256) void seqlen_kernel(const int* __restrict__ mask,
                                                     const float* __restrict__ chain,
                                                     float* __restrict__ out_seqlen,
                                                     float* __restrict__ out_chain,
                                                     int* __restrict__ ws_seqlen) {
    const int b = blockIdx.x;
    const int tid = threadIdx.x;
    int s = 0;
    for (int t = tid; t < TT; t += 256) s += mask[b * TT + t];
#pragma unroll
    for (int off = 32; off >= 1; off >>= 1) s += __shfl_down(s, off, 64);
    __shared__ int red[4];
    if ((tid & 63) == 0) red[tid >> 6] = s;
    __syncthreads();
    if (tid == 0) {
        int tot = red[0] + red[1] + red[2] + red[3];
        out_seqlen[b] = (float)tot;
        ws_seqlen[b] = tot;
    }
    if (b == 0) {
        for (int i = tid; i < KK * KK; i += 256) out_chain[i] = chain[i];
    }
}

// ---------------------------------------------------------------------------
// Kernel 3: GRU scan — 3-wave gate split, weights in LDS (RA-proof).
// The compiler refuses to keep a 64-float weight array in VGPRs (R2-R6:
// VGPR counts 44..132 regardless of hints -> per-step re-load from memory).
// Fix: weights live in LDS. Row r = gate*64+lane holds its 64 weights as 16
// float4 chunks, rotated by (chunk+row)&15 so the per-lane ds_read_b128
// stream spreads across all 8 bank windows. 48 KB LDS traffic per step/CU.
// h broadcast by readlane; one barrier/step; double-buffered gate exchange.
// ---------------------------------------------------------------------------
#define BCAST(v, l) __int_as_float(__builtin_amdgcn_readlane(__float_as_int(v), (l)))

__global__ __launch_bounds__(192)
void gru_kernel(const float* __restrict__ xp,
                const float* __restrict__ Wr,
                const float* __restrict__ gbias,
                const int* __restrict__ mask,
                float* __restrict__ hidden) {
    const int b = blockIdx.x;
    const int tid = threadIdx.x;               // row = tid = w*64+j
    const int w = tid >> 6;                    // gate: 0=z, 1=r, 2=h-cand
    const int j = tid & 63;
    __shared__ float4 WL[G3 * 16];             // 49152 B, rotated chunks
    __shared__ float gbuf[2][4 * HH];          // z | r | rh | xh, double-buffered
    // stage weights: WL[row*16 + ((c+row)&15)] = Wr[4c..4c+3][row]
    for (int c = 0; c < 16; ++c) {
        float4 v;
        v.x = Wr[(4 * c + 0) * G3 + tid];
        v.y = Wr[(4 * c + 1) * G3 + tid];
        v.z = Wr[(4 * c + 2) * G3 + tid];
        v.w = Wr[(4 * c + 3) * G3 + tid];
        WL[tid * 16 + ((c + tid) & 15)] = v;
    }
    const float bw = gbias[G3 + tid];          // recurrent bias for (gate,lane)
    float h = 0.f;                             // lane j holds h_j (per-wave copy)
    const float* xpb = xp + (size_t)b * TT * G3;
    const int bTT = b * TT;
    __syncthreads();
    // 2-deep prefetch of this thread's x-projection element + mask
    float xv0 = xpb[tid];
    float xv1 = xpb[G3 + tid];
    int m0 = mask[bTT];
    int m1 = mask[bTT + 1];
    const int rowbase = tid * 16;
    for (int t = 0; t < TT; ++t) {
        const int tn = (t + 2 < TT) ? t + 2 : TT - 1;
        float xv2 = xpb[(size_t)tn * G3 + tid];
        int m2 = mask[bTT + tn];
        // matvec for this gate: 16 x (ds_read_b128 + 4 readlane + 4 fmac)
        float a0 = bw, a1 = 0.f, a2 = 0.f, a3 = 0.f;
#pragma unroll
        for (int c = 0; c < 16; ++c) {
            float4 wv = WL[rowbase + ((c + tid) & 15)];
            a0 += BCAST(h, 4 * c + 0) * wv.x;
            a1 += BCAST(h, 4 * c + 1) * wv.y;
            a2 += BCAST(h, 4 * c + 2) * wv.z;
            a3 += BCAST(h, 4 * c + 3) * wv.w;
        }
        float a = (a0 + a1) + (a2 + a3);
        float g = (w == 2) ? a : 1.f / (1.f + __expf(-(xv0 + a)));
        const int p = t & 1;
        gbuf[p][w * HH + j] = g;
        if (w == 2) gbuf[p][3 * HH + j] = xv0;   // xh
        __syncthreads();
        float z  = gbuf[p][j];
        float r  = gbuf[p][HH + j];
        float rh = gbuf[p][2 * HH + j];
        float xh = gbuf[p][3 * HH + j];
        float y = xh + r * rh;
        float hh = 1.f - 2.f / (1.f + __expf(2.f * y));   // tanh(y)
        float hn = z * h + (1.f - z) * hh;
        hn = (m0 != 0) ? hn : h;
        if (w == 0) hidden[((size_t)(bTT + t)) * HH + j] = hn;
        h = hn;
        xv0 = xv1; xv1 = xv2; m0 = m1; m1 = m2;
    }
}

// ---------------------------------------------------------------------------
// Kernel 4: potentials[row,k] = hidden[row,:]@Dk[:,k] + db[k] (+ boundaries)
// ---------------------------------------------------------------------------
#define PR 8
__global__ __launch_bounds__(256) void pot_kernel(const float* __restrict__ hidden,
                                                  const float* __restrict__ Dk,
                                                  const float* __restrict__ db,
                                                  const float* __restrict__ lb,
                                                  const float* __restrict__ rb,
                                                  const int* __restrict__ slen,
                                                  float* __restrict__ pot) {
    __shared__ float Hs[PR * HH];
    __shared__ float Dks[HH * KK];
    const int tid = threadIdx.x;
    const int k = tid & (KK - 1);
    const int rl = tid >> 5;                   // 0..7
    const size_t row0 = (size_t)blockIdx.x * PR;
    for (int idx = tid; idx < PR * HH; idx += 256) Hs[idx] = hidden[row0 * HH + idx];
    for (int idx = tid; idx < HH * KK; idx += 256) Dks[idx] = Dk[idx];
    __syncthreads();
    float acc = db[k];
#pragma unroll
    for (int i = 0; i < HH; i += 4) {
        float4 hv = *(const float4*)&Hs[rl * HH + i];
        acc += hv.x * Dks[i * KK + k] + hv.y * Dks[(i + 1) * KK + k]
             + hv.z * Dks[(i + 2) * KK + k] + hv.w * Dks[(i + 3) * KK + k];
    }
    const size_t row = row0 + rl;
    const int t = (int)(row & (TT - 1));
    const int bb = (int)(row >> 10);
    if (t == 0) acc += lb[k];
    if (t == slen[bb] - 1) acc += rb[k];
    pot[row * KK + k] = acc;
}

// ---------------------------------------------------------------------------
// Kernel 5: Viterbi — R5 half-split structure (fits registers; R6's 32-wide
// column layout spilled at VGPR=88 and ran 1250 us). Lane k&31, half hf:
// 16 bpermutes + depth-4 tree + one cross-half hop. 4-deep pot prefetch.
// ---------------------------------------------------------------------------
__global__ __launch_bounds__(256) void viterbi_kernel(const float* __restrict__ pot,
                                                      const float* __restrict__ chain,
                                                      float* __restrict__ decoded) {
    const int b = blockIdx.x;
    const int tid = threadIdx.x;
    __shared__ unsigned char bp[(TT - 1) * KK];        // 32736 B
    __shared__ unsigned char table[32 * 32 * KK];      // 32 chunks x 32 pos x 32 cand
    __shared__ int ent[32];
    __shared__ int last_tag_s;
    const float* pb = pot + (size_t)b * TT * KK;

    if (tid < 64) {
        const int k = tid & 31;
        const int hf = tid >> 5;                       // half: k_from in [16h,16h+16)
        float ccol[16];
        int addr[16];
#pragma unroll
        for (int m = 0; m < 16; ++m) {
            ccol[m] = chain[(hf * 16 + m) * KK + k];
            addr[m] = (hf * 16 + m) * 4;
        }
        const int addrx = (tid ^ 32) * 4;
        float s = pb[k];
        // 4-deep prefetch ring (overruns for b=127 land in slen/chain area
        // of d_out: allocated, values unused)
        float pv0 = pb[1 * KK + k];
        float pv1 = pb[2 * KK + k];
        float pv2 = pb[3 * KK + k];
        float pv3 = pb[4 * KK + k];
        for (int t = 1; t < TT; ++t) {
            float pv = pv0;
            pv0 = pv1; pv1 = pv2; pv2 = pv3;
            pv3 = pb[(size_t)(t + 4) * KK + k];
            const int si = __float_as_int(s);
            float c[16];
#pragma unroll
            for (int m = 0; m < 16; ++m)
                c[m] = __int_as_float(__builtin_amdgcn_ds_bpermute(addr[m], si)) + ccol[m];
            float v1[8]; int i1[8];
#pragma unroll
            for (int p = 0; p < 8; ++p) {
                bool tk = c[2 * p + 1] > c[2 * p];
                v1[p] = tk ? c[2 * p + 1] : c[2 * p];
                i1[p] = hf * 16 + (tk ? 2 * p + 1 : 2 * p);
            }
            float v2[4]; int i2[4];
#pragma unroll
            for (int p = 0; p < 4; ++p) {
                bool tk = v1[2 * p + 1] > v1[2 * p];
                v2[p] = tk ? v1[2 * p + 1] : v1[2 * p];
                i2[p] = tk ? i1[2 * p + 1] : i1[2 * p];
            }
            float v3[2]; int i3[2];
#pragma unroll
            for (int p = 0; p < 2; ++p) {
                bool tk = v2[2 * p + 1] > v2[2 * p];
                v3[p] = tk ? v2[2 * p + 1] : v2[2 * p];
                i3[p] = tk ? i2[2 * p + 1] : i2[2 * p];
            }
            bool tk = v3[1] > v3[0];
            float bv = tk ? v3[1] : v3[0];
            int bi = tk ? i3[1] : i3[0];
            float ov = __int_as_float(__builtin_amdgcn_ds_bpermute(addrx, __float_as_int(bv)));
            int   oi = __builtin_amdgcn_ds_bpermute(addrx, bi);
            bool take = (ov > bv) || (ov == bv && oi < bi);
            if (take) { bv = ov; bi = oi; }
            if (tid < 32) bp[(t - 1) * KK + k] = (unsigned char)bi;
            s = bv + pv;
        }
        float bv = s; int bi = k;
#pragma unroll
        for (int d = 16; d >= 1; d >>= 1) {
            float ov = __shfl_xor(bv, d, 64);
            int   oi = __shfl_xor(bi, d, 64);
            bool take = (ov > bv) || (ov == bv && oi < bi);
            if (take) { bv = ov; bi = oi; }
        }
        if (tid == 0) last_tag_s = bi;
    }
    __syncthreads();
    {
        const int k = tid & 31;
        const int cs = tid >> 5;                       // 0..7
        for (int cc = 0; cc < 4; ++cc) {
            const int c = cs * 4 + cc;
            int tag = k;
            for (int l = 31; l >= 0; --l) {
                const int t = c * 32 + l;
                if (t < TT - 1) tag = bp[t * KK + tag];
                table[(c * 32 + l) * KK + k] = (unsigned char)tag;
            }
        }
    }
    __syncthreads();
    if (tid == 0) {
        int e = last_tag_s;
        ent[31] = e;
        for (int c = 30; c >= 0; --c) { e = table[(c + 1) * 32 * KK + e]; ent[c] = e; }
    }
    __syncthreads();
    for (int t = tid; t < TT; t += 256) {
        const int c = t >> 5, l = t & 31;
        decoded[(size_t)b * TT + t] = (float)table[(c * 32 + l) * KK + ent[c]];
    }
}

// ---------------------------------------------------------------------------
extern "C" void kernel_launch(void* const* d_in, const int* in_sizes, int n_in,
                              void* d_out, int out_size, void* d_ws, size_t ws_size,
                              hipStream_t stream) {
    const float* X     = (const float*)d_in[0];
    const int*   mask  = (const int*)d_in[1];
    const float* Wk    = (const float*)d_in[2];   // [128,192]
    const float* Wr    = (const float*)d_in[3];   // [64,192]
    const float* gb    = (const float*)d_in[4];   // [2,192]
    const float* Dk    = (const float*)d_in[5];   // [64,32]
    const float* db    = (const float*)d_in[6];   // [32]
    const float* chain = (const float*)d_in[7];   // [32,32]
    const float* lb    = (const float*)d_in[8];
    const float* rb    = (const float*)d_in[9];

    float* out = (float*)d_out;
    float* out_dec  = out;                                   // [B,T]
    float* out_pot  = out + (size_t)BB * TT;                 // [B,T,K]
    float* out_slen = out + (size_t)BB * TT + (size_t)BB * TT * KK;        // [B]
    float* out_chn  = out_slen + BB;                         // [K,K]

    float* ws = (float*)d_ws;
    float* xp     = ws;                                      // [B*T,192]
    float* hidden = ws + (size_t)BB * TT * G3;               // [B*T,64]
    int*   slen_i = (int*)(hidden + (size_t)BB * TT * HH);   // [B]

    xproj_kernel<<<dim3((BB * TT) / 64, 3), dim3(256), 0, stream>>>(X, Wk, gb, xp);
    seqlen_kernel<<<dim3(BB), dim3(256), 0, stream>>>(mask, chain, out_slen, out_chn, slen_i);
    gru_kernel<<<dim3(BB), dim3(192), 0, stream>>>(xp, Wr, gb, mask, hidden);
    pot_kernel<<<dim3((BB * TT) / PR), dim3(256), 0, stream>>>(hidden, Dk, db, lb, rb, slen_i, out_pot);
    viterbi_kernel<<<dim3(BB), dim3(256), 0, stream>>>(out_pot, chain, out_dec);
}

// Round 8
// 1011.345 us; speedup vs baseline: 2.2974x; 1.4122x over previous
//
#include <hip/hip_runtime.h>
#include <math.h>

#define BB 128
#define TT 1024
#define DD 128
#define HH 64
#define G3 192   // 3*H
#define KK 32

// ---------------------------------------------------------------------------
// Kernel 1: xproj[B*T,192] = X[B*T,128] @ Wk[128,192] + b0  (unchanged)
// ---------------------------------------------------------------------------
__global__ __launch_bounds__(256, 2) void xproj_kernel(const float* __restrict__ X,
                                                       const float* __restrict__ Wk,
                                                       const float* __restrict__ gbias,
                                                       float* __restrict__ xp) {
    __shared__ float Xs[64 * 132];
    __shared__ float Ws[128 * 68];
    const int tid = threadIdx.x;
    const int row0 = blockIdx.x * 64;
    const int cg = blockIdx.y;
#pragma unroll
    for (int it = 0; it < 8; ++it) {
        int idx = it * 1024 + tid * 4;
        int r = idx >> 7, c = idx & 127;
        float4 v = *(const float4*)&X[((size_t)(row0 + r)) * DD + c];
        *(float4*)&Xs[r * 132 + c] = v;
    }
#pragma unroll
    for (int it = 0; it < 8; ++it) {
        int idx = it * 1024 + tid * 4;
        int k = idx >> 6, c = idx & 63;
        float4 v = *(const float4*)&Wk[(size_t)k * G3 + cg * 64 + c];
        *(float4*)&Ws[k * 68 + c] = v;
    }
    __syncthreads();
    const int tr = tid >> 4, tc = tid & 15;
    const int r0 = tr * 4, c0 = tc * 4;
    float acc[4][4];
#pragma unroll
    for (int r = 0; r < 4; ++r)
#pragma unroll
        for (int c = 0; c < 4; ++c) acc[r][c] = 0.f;
#pragma unroll 4
    for (int k = 0; k < DD; k += 4) {
        float a[4][4];
#pragma unroll
        for (int r = 0; r < 4; ++r) {
            float4 t = *(const float4*)&Xs[(r0 + r) * 132 + k];
            a[r][0] = t.x; a[r][1] = t.y; a[r][2] = t.z; a[r][3] = t.w;
        }
#pragma unroll
        for (int kk = 0; kk < 4; ++kk) {
            float4 b = *(const float4*)&Ws[(k + kk) * 68 + c0];
#pragma unroll
            for (int r = 0; r < 4; ++r) {
                acc[r][0] += a[r][kk] * b.x;
                acc[r][1] += a[r][kk] * b.y;
                acc[r][2] += a[r][kk] * b.z;
                acc[r][3] += a[r][kk] * b.w;
            }
        }
    }
    float4 bias = *(const float4*)&gbias[cg * 64 + c0];
#pragma unroll
    for (int r = 0; r < 4; ++r) {
        float4 o;
        o.x = acc[r][0] + bias.x; o.y = acc[r][1] + bias.y;
        o.z = acc[r][2] + bias.z; o.w = acc[r][3] + bias.w;
        *(float4*)&xp[((size_t)(row0 + r0 + r)) * G3 + cg * 64 + c0] = o;
    }
}

// ---------------------------------------------------------------------------
// Kernel 2: FUSED GRU + potentials + Viterbi. One block per batch, 4 waves:
//   waves 0-2: GRU gate-split producer (weights asm-forced into VGPRs —
//              blocks the remat heuristic that spilled them in R2-R7).
//   wave 3:    consumer — computes pot row t (h from LDS ring, Dk in regs),
//              writes pot to d_out, runs the Viterbi transition, stores bp.
// The two ~550us serial scans now overlap; hidden[] global traffic is gone.
// Pipeline: gru writes h(t) to hbuf[t&3] post-barrier(t); wave 3 reads
// h(i-1) post-barrier(i). Both loops execute exactly TT+1 barriers.
// ---------------------------------------------------------------------------
#define BCAST(v, l) __int_as_float(__builtin_amdgcn_readlane(__float_as_int(v), (l)))

__global__ __launch_bounds__(256, 1)
void fused_kernel(const float* __restrict__ xp,
                  const float* __restrict__ Wr,
                  const float* __restrict__ gbias,
                  const int* __restrict__ mask,
                  const float* __restrict__ Dk,
                  const float* __restrict__ db,
                  const float* __restrict__ chain,
                  const float* __restrict__ lb,
                  const float* __restrict__ rb,
                  float* __restrict__ out_pot,
                  float* __restrict__ out_dec,
                  float* __restrict__ out_slen,
                  float* __restrict__ out_chn) {
    const int b = blockIdx.x;
    const int tid = threadIdx.x;
    const int w = tid >> 6;                    // 0..3
    const int l = tid & 63;
    const int bTT = b * TT;

    __shared__ unsigned char bp[(TT - 1) * KK];        // 32736 B
    __shared__ unsigned char table[32 * 32 * KK];      // 32768 B
    __shared__ int ent[32];
    __shared__ int last_tag_s;
    __shared__ float gbuf[2][4 * HH];                  // z|r|rh|xh double-buf
    __shared__ __align__(16) float hbuf[4][HH];        // h ring

    if (w < 3) {
        // ================= GRU producer waves =================
        const int j = l;
        float wg[HH];
#pragma unroll
        for (int i2 = 0; i2 < HH; ++i2) wg[i2] = Wr[i2 * G3 + w * HH + j];
#pragma unroll
        for (int i2 = 0; i2 < HH; ++i2) asm volatile("" : "+v"(wg[i2]));
        const float bw = gbias[G3 + w * HH + j];
        float h = 0.f;
        const float* xpb = xp + (size_t)bTT * G3;
        float xv0 = xpb[tid];
        float xv1 = xpb[G3 + tid];
        int m0 = mask[bTT];
        int m1 = mask[bTT + 1];
        for (int i = 0; i <= TT; ++i) {
            if (i < TT) {
                float a0 = bw, a1 = 0.f, a2 = 0.f, a3 = 0.f;
#pragma unroll
                for (int c = 0; c < HH; c += 4) {
                    a0 += BCAST(h, c + 0) * wg[c + 0];
                    a1 += BCAST(h, c + 1) * wg[c + 1];
                    a2 += BCAST(h, c + 2) * wg[c + 2];
                    a3 += BCAST(h, c + 3) * wg[c + 3];
                }
                float a = (a0 + a1) + (a2 + a3);
                float g = (w == 2) ? a : 1.f / (1.f + __expf(-(xv0 + a)));
                gbuf[i & 1][w * HH + j] = g;
                if (w == 2) gbuf[i & 1][3 * HH + j] = xv0;
            }
            __syncthreads();
            if (i < TT) {
                float z  = gbuf[i & 1][j];
                float r  = gbuf[i & 1][HH + j];
                float rh = gbuf[i & 1][2 * HH + j];
                float xh = gbuf[i & 1][3 * HH + j];
                float y = xh + r * rh;
                float hh = 1.f - 2.f / (1.f + __expf(2.f * y));   // tanh(y)
                float hn = z * h + (1.f - z) * hh;
                hn = (m0 != 0) ? hn : h;
                h = hn;
                if (w == 0) hbuf[i & 3][j] = hn;
                const int t2 = (i + 2 < TT) ? i + 2 : TT - 1;
                xv0 = xv1; xv1 = xpb[(size_t)t2 * G3 + tid];
                m0 = m1;  m1 = mask[bTT + t2];
            }
        }
    } else {
        // ================= Viterbi consumer wave =================
        const int k = l & 31;
        const int hf = l >> 5;
        int sl = 0;
#pragma unroll
        for (int q = 0; q < 16; ++q) sl += mask[bTT + q * 64 + l];
#pragma unroll
        for (int d = 32; d >= 1; d >>= 1) sl += __shfl_xor(sl, d, 64);
        if (l == 0) out_slen[b] = (float)sl;
        float dk[HH];
#pragma unroll
        for (int i2 = 0; i2 < HH; ++i2) dk[i2] = Dk[i2 * KK + k];
#pragma unroll
        for (int i2 = 0; i2 < HH; ++i2) asm volatile("" : "+v"(dk[i2]));
        float ccol[16];
        int addr[16];
#pragma unroll
        for (int m = 0; m < 16; ++m) {
            ccol[m] = chain[(hf * 16 + m) * KK + k];
            addr[m] = (hf * 16 + m) * 4;
        }
#pragma unroll
        for (int m = 0; m < 16; ++m) asm volatile("" : "+v"(ccol[m]));
        const int addrx = (l ^ 32) * 4;
        const float dbk = db[k], lbk = lb[k], rbk = rb[k];
        float s = 0.f;
        float* potb = out_pot + (size_t)bTT * KK;
        for (int i = 0; i <= TT; ++i) {
            __syncthreads();
            if (i >= 1) {
                const int t = i - 1;
                const float4* hv4 = (const float4*)&hbuf[t & 3][0];
                float p0 = dbk, p1 = 0.f, p2 = 0.f, p3 = 0.f;
#pragma unroll
                for (int c = 0; c < 16; ++c) {
                    float4 hv = hv4[c];
                    p0 += hv.x * dk[4 * c + 0];
                    p1 += hv.y * dk[4 * c + 1];
                    p2 += hv.z * dk[4 * c + 2];
                    p3 += hv.w * dk[4 * c + 3];
                }
                float pot = (p0 + p1) + (p2 + p3);
                if (t == 0) pot += lbk;
                if (t == sl - 1) pot += rbk;
                if (l < 32) potb[(size_t)t * KK + k] = pot;
                if (t == 0) {
                    s = pot;
                } else {
                    const int si = __float_as_int(s);
                    float c[16];
#pragma unroll
                    for (int m = 0; m < 16; ++m)
                        c[m] = __int_as_float(__builtin_amdgcn_ds_bpermute(addr[m], si)) + ccol[m];
                    float v1[8]; int i1[8];
#pragma unroll
                    for (int p = 0; p < 8; ++p) {
                        bool tk = c[2 * p + 1] > c[2 * p];
                        v1[p] = tk ? c[2 * p + 1] : c[2 * p];
                        i1[p] = hf * 16 + (tk ? 2 * p + 1 : 2 * p);
                    }
                    float v2[4]; int i2[4];
#pragma unroll
                    for (int p = 0; p < 4; ++p) {
                        bool tk = v1[2 * p + 1] > v1[2 * p];
                        v2[p] = tk ? v1[2 * p + 1] : v1[2 * p];
                        i2[p] = tk ? i1[2 * p + 1] : i1[2 * p];
                    }
                    float v3[2]; int i3[2];
#pragma unroll
                    for (int p = 0; p < 2; ++p) {
                        bool tk = v2[2 * p + 1] > v2[2 * p];
                        v3[p] = tk ? v2[2 * p + 1] : v2[2 * p];
                        i3[p] = tk ? i2[2 * p + 1] : i2[2 * p];
                    }
                    bool tk = v3[1] > v3[0];
                    float bv = tk ? v3[1] : v3[0];
                    int bi = tk ? i3[1] : i3[0];
                    float ov = __int_as_float(__builtin_amdgcn_ds_bpermute(addrx, __float_as_int(bv)));
                    int   oi = __builtin_amdgcn_ds_bpermute(addrx, bi);
                    bool take = (ov > bv) || (ov == bv && oi < bi);
                    if (take) { bv = ov; bi = oi; }
                    if (l < 32) bp[(t - 1) * KK + k] = (unsigned char)bi;
                    s = bv + pot;
                }
            }
        }
        // final first-index argmax over s
        float bv = s; int bi = k;
#pragma unroll
        for (int d = 16; d >= 1; d >>= 1) {
            float ov = __shfl_xor(bv, d, 64);
            int   oi = __shfl_xor(bi, d, 64);
            bool take = (ov > bv) || (ov == bv && oi < bi);
            if (take) { bv = ov; bi = oi; }
        }
        if (l == 0) last_tag_s = bi;
    }
    __syncthreads();
    // ---- Phase A: per chunk c (32 steps), chase all 32 candidate tags ----
    {
        const int k = tid & 31;
        const int cs = tid >> 5;                       // 0..7
        for (int cc = 0; cc < 4; ++cc) {
            const int c = cs * 4 + cc;
            int tag = k;
            for (int ll = 31; ll >= 0; --ll) {
                const int t = c * 32 + ll;
                if (t < TT - 1) tag = bp[t * KK + tag];
                table[(c * 32 + ll) * KK + k] = (unsigned char)tag;
            }
        }
    }
    __syncthreads();
    if (tid == 0) {                                    // Phase B: stitch
        int e = last_tag_s;
        ent[31] = e;
        for (int c = 30; c >= 0; --c) { e = table[(c + 1) * 32 * KK + e]; ent[c] = e; }
    }
    __syncthreads();
    for (int t = tid; t < TT; t += 256) {              // Phase C: emit
        const int c = t >> 5, ll = t & 31;
        out_dec[(size_t)bTT + t] = (float)table[(c * 32 + ll) * KK + ent[c]];
    }
    if (b == 0) {
        for (int i2 = tid; i2 < KK * KK; i2 += 256) out_chn[i2] = chain[i2];
    }
}

// ---------------------------------------------------------------------------
extern "C" void kernel_launch(void* const* d_in, const int* in_sizes, int n_in,
                              void* d_out, int out_size, void* d_ws, size_t ws_size,
                              hipStream_t stream) {
    const float* X     = (const float*)d_in[0];
    const int*   mask  = (const int*)d_in[1];
    const float* Wk    = (const float*)d_in[2];   // [128,192]
    const float* Wr    = (const float*)d_in[3];   // [64,192]
    const float* gb    = (const float*)d_in[4];   // [2,192]
    const float* Dk    = (const float*)d_in[5];   // [64,32]
    const float* db    = (const float*)d_in[6];   // [32]
    const float* chain = (const float*)d_in[7];   // [32,32]
    const float* lb    = (const float*)d_in[8];
    const float* rb    = (const float*)d_in[9];

    float* out = (float*)d_out;
    float* out_dec  = out;                                   // [B,T]
    float* out_pot  = out + (size_t)BB * TT;                 // [B,T,K]
    float* out_slen = out + (size_t)BB * TT + (size_t)BB * TT * KK;        // [B]
    float* out_chn  = out_slen + BB;                         // [K,K]

    float* xp = (float*)d_ws;                                // [B*T,192]

    xproj_kernel<<<dim3((BB * TT) / 64, 3), dim3(256), 0, stream>>>(X, Wk, gb, xp);
    fused_kernel<<<dim3(BB), dim3(256), 0, stream>>>(xp, Wr, gb, mask, Dk, db, chain,
                                                     lb, rb, out_pot, out_dec,
                                                     out_slen, out_chn);
}

// Round 9
// 901.201 us; speedup vs baseline: 2.5782x; 1.1222x over previous
//
#include <hip/hip_runtime.h>
#include <math.h>

#define BB 128
#define TT 1024
#define DD 128
#define HH 64
#define G3 192   // 3*H
#define KK 32

// ---------------------------------------------------------------------------
// Kernel 1: xproj[B*T,192] = X[B*T,128] @ Wk[128,192] + b0  (unchanged)
// ---------------------------------------------------------------------------
__global__ __launch_bounds__(256, 2) void xproj_kernel(const float* __restrict__ X,
                                                       const float* __restrict__ Wk,
                                                       const float* __restrict__ gbias,
                                                       float* __restrict__ xp) {
    __shared__ float Xs[64 * 132];
    __shared__ float Ws[128 * 68];
    const int tid = threadIdx.x;
    const int row0 = blockIdx.x * 64;
    const int cg = blockIdx.y;
#pragma unroll
    for (int it = 0; it < 8; ++it) {
        int idx = it * 1024 + tid * 4;
        int r = idx >> 7, c = idx & 127;
        float4 v = *(const float4*)&X[((size_t)(row0 + r)) * DD + c];
        *(float4*)&Xs[r * 132 + c] = v;
    }
#pragma unroll
    for (int it = 0; it < 8; ++it) {
        int idx = it * 1024 + tid * 4;
        int k = idx >> 6, c = idx & 63;
        float4 v = *(const float4*)&Wk[(size_t)k * G3 + cg * 64 + c];
        *(float4*)&Ws[k * 68 + c] = v;
    }
    __syncthreads();
    const int tr = tid >> 4, tc = tid & 15;
    const int r0 = tr * 4, c0 = tc * 4;
    float acc[4][4];
#pragma unroll
    for (int r = 0; r < 4; ++r)
#pragma unroll
        for (int c = 0; c < 4; ++c) acc[r][c] = 0.f;
#pragma unroll 4
    for (int k = 0; k < DD; k += 4) {
        float a[4][4];
#pragma unroll
        for (int r = 0; r < 4; ++r) {
            float4 t = *(const float4*)&Xs[(r0 + r) * 132 + k];
            a[r][0] = t.x; a[r][1] = t.y; a[r][2] = t.z; a[r][3] = t.w;
        }
#pragma unroll
        for (int kk = 0; kk < 4; ++kk) {
            float4 b = *(const float4*)&Ws[(k + kk) * 68 + c0];
#pragma unroll
            for (int r = 0; r < 4; ++r) {
                acc[r][0] += a[r][kk] * b.x;
                acc[r][1] += a[r][kk] * b.y;
                acc[r][2] += a[r][kk] * b.z;
                acc[r][3] += a[r][kk] * b.w;
            }
        }
    }
    float4 bias = *(const float4*)&gbias[cg * 64 + c0];
#pragma unroll
    for (int r = 0; r < 4; ++r) {
        float4 o;
        o.x = acc[r][0] + bias.x; o.y = acc[r][1] + bias.y;
        o.z = acc[r][2] + bias.z; o.w = acc[r][3] + bias.w;
        *(float4*)&xp[((size_t)(row0 + r0 + r)) * G3 + cg * 64 + c0] = o;
    }
}

// ---------------------------------------------------------------------------
// Kernel 2: FUSED GRU + potentials + Viterbi — 3-stage wave pipeline.
//   waves 0-2: GRU gate-split producer (weights asm-forced into VGPRs)
//   wave 3:    pot stage — h(t-2) -> pot row (Dk in regs), potbuf ring+global
//   wave 4:    viterbi stage — potbuf(t-2) -> transition (bpermute+tree)
//   wave 5:    idle in main loop, helps backtrack.
// R8's single consumer wave serialized pot-matvec (16 ds_read_b128) AND 17
// bpermutes on one LDS pipe (~600+cyc leg > GRU leg). Split halves each leg.
// Phase i: pre(i) | barrier(i) | post(i).  h(t) written post(t) by wave 0;
// pot reads it pre(t+2) (barrier t+1 between); potbuf written pre(i), read
// post(i) by viterbi. All waves run TT+2 barriers.
// ---------------------------------------------------------------------------
#define BCAST(v, l) __int_as_float(__builtin_amdgcn_readlane(__float_as_int(v), (l)))

__global__ __launch_bounds__(384, 1)
void fused_kernel(const float* __restrict__ xp,
                  const float* __restrict__ Wr,
                  const float* __restrict__ gbias,
                  const int* __restrict__ mask,
                  const float* __restrict__ Dk,
                  const float* __restrict__ db,
                  const float* __restrict__ chain,
                  const float* __restrict__ lb,
                  const float* __restrict__ rb,
                  float* __restrict__ out_pot,
                  float* __restrict__ out_dec,
                  float* __restrict__ out_slen,
                  float* __restrict__ out_chn) {
    const int b = blockIdx.x;
    const int tid = threadIdx.x;
    const int w = tid >> 6;                    // 0..5
    const int l = tid & 63;
    const int bTT = b * TT;

    __shared__ unsigned char bp[(TT - 1) * KK];        // 32736 B
    __shared__ unsigned char table[32 * 32 * KK];      // 32768 B
    __shared__ int ent[32];
    __shared__ int last_tag_s;
    __shared__ float gbuf[2][4 * HH];                  // z|r|rh|xh double-buf
    __shared__ __align__(16) float hbuf[4][HH];        // h ring
    __shared__ float potbuf[4][KK];                    // pot ring

    if (w < 3) {
        // ================= GRU producer waves =================
        const int j = l;
        float wg[HH];
#pragma unroll
        for (int i2 = 0; i2 < HH; ++i2) wg[i2] = Wr[i2 * G3 + w * HH + j];
#pragma unroll
        for (int i2 = 0; i2 < HH; ++i2) asm volatile("" : "+v"(wg[i2]));
        const float bw = gbias[G3 + w * HH + j];
        float h = 0.f;
        const float* xpb = xp + (size_t)bTT * G3;
        float xv0 = xpb[tid];
        float xv1 = xpb[G3 + tid];
        int m0 = mask[bTT];
        int m1 = mask[bTT + 1];
        for (int i = 0; i < TT + 2; ++i) {
            if (i < TT) {
                float a0 = bw, a1 = 0.f, a2 = 0.f, a3 = 0.f;
#pragma unroll
                for (int c = 0; c < HH; c += 4) {
                    a0 += BCAST(h, c + 0) * wg[c + 0];
                    a1 += BCAST(h, c + 1) * wg[c + 1];
                    a2 += BCAST(h, c + 2) * wg[c + 2];
                    a3 += BCAST(h, c + 3) * wg[c + 3];
                }
                float a = (a0 + a1) + (a2 + a3);
                float g = (w == 2) ? a : 1.f / (1.f + __expf(-(xv0 + a)));
                gbuf[i & 1][w * HH + j] = g;
                if (w == 2) gbuf[i & 1][3 * HH + j] = xv0;
            }
            __syncthreads();
            if (i < TT) {
                float z  = gbuf[i & 1][j];
                float r  = gbuf[i & 1][HH + j];
                float rh = gbuf[i & 1][2 * HH + j];
                float xh = gbuf[i & 1][3 * HH + j];
                float y = xh + r * rh;
                float hh = 1.f - 2.f / (1.f + __expf(2.f * y));   // tanh(y)
                float hn = z * h + (1.f - z) * hh;
                hn = (m0 != 0) ? hn : h;
                h = hn;
                if (w == 0) hbuf[i & 3][j] = hn;
                const int t2 = (i + 2 < TT) ? i + 2 : TT - 1;
                xv0 = xv1; xv1 = xpb[(size_t)t2 * G3 + tid];
                m0 = m1;  m1 = mask[bTT + t2];
            }
        }
    } else if (w == 3) {
        // ================= pot stage =================
        const int k = l & 31;
        int sl = 0;
#pragma unroll
        for (int q = 0; q < 16; ++q) sl += mask[bTT + q * 64 + l];
#pragma unroll
        for (int d = 32; d >= 1; d >>= 1) sl += __shfl_xor(sl, d, 64);
        if (l == 0) out_slen[b] = (float)sl;
        float dk[HH];
#pragma unroll
        for (int i2 = 0; i2 < HH; ++i2) dk[i2] = Dk[i2 * KK + k];
#pragma unroll
        for (int i2 = 0; i2 < HH; ++i2) asm volatile("" : "+v"(dk[i2]));
        const float dbk = db[k], lbk = lb[k], rbk = rb[k];
        float* potb = out_pot + (size_t)bTT * KK;
        for (int i = 0; i < TT + 2; ++i) {
            const int t = i - 2;
            if (t >= 0 && t < TT) {
                const float4* hv4 = (const float4*)&hbuf[t & 3][0];
                float p0 = dbk, p1 = 0.f, p2 = 0.f, p3 = 0.f;
#pragma unroll
                for (int c = 0; c < 16; ++c) {
                    float4 hv = hv4[c];
                    p0 += hv.x * dk[4 * c + 0];
                    p1 += hv.y * dk[4 * c + 1];
                    p2 += hv.z * dk[4 * c + 2];
                    p3 += hv.w * dk[4 * c + 3];
                }
                float pot = (p0 + p1) + (p2 + p3);
                if (t == 0) pot += lbk;
                if (t == sl - 1) pot += rbk;
                if (l < 32) {
                    potbuf[t & 3][k] = pot;
                    potb[(size_t)t * KK + k] = pot;
                }
            }
            __syncthreads();
        }
    } else if (w == 4) {
        // ================= viterbi stage =================
        const int k = l & 31;
        const int hf = l >> 5;
        float ccol[16];
        int addr[16];
#pragma unroll
        for (int m = 0; m < 16; ++m) {
            ccol[m] = chain[(hf * 16 + m) * KK + k];
            addr[m] = (hf * 16 + m) * 4;
        }
#pragma unroll
        for (int m = 0; m < 16; ++m) asm volatile("" : "+v"(ccol[m]));
        const int addrx = (l ^ 32) * 4;
        float s = 0.f;
        for (int i = 0; i < TT + 2; ++i) {
            __syncthreads();
            const int t = i - 2;
            if (t >= 0 && t < TT) {
                float pot = potbuf[t & 3][k];
                if (t == 0) {
                    s = pot;
                } else {
                    const int si = __float_as_int(s);
                    float c[16];
#pragma unroll
                    for (int m = 0; m < 16; ++m)
                        c[m] = __int_as_float(__builtin_amdgcn_ds_bpermute(addr[m], si)) + ccol[m];
                    float v1[8]; int i1[8];
#pragma unroll
                    for (int p = 0; p < 8; ++p) {
                        bool tk = c[2 * p + 1] > c[2 * p];
                        v1[p] = tk ? c[2 * p + 1] : c[2 * p];
                        i1[p] = hf * 16 + (tk ? 2 * p + 1 : 2 * p);
                    }
                    float v2[4]; int i2[4];
#pragma unroll
                    for (int p = 0; p < 4; ++p) {
                        bool tk = v1[2 * p + 1] > v1[2 * p];
                        v2[p] = tk ? v1[2 * p + 1] : v1[2 * p];
                        i2[p] = tk ? i1[2 * p + 1] : i1[2 * p];
                    }
                    float v3[2]; int i3[2];
#pragma unroll
                    for (int p = 0; p < 2; ++p) {
                        bool tk = v2[2 * p + 1] > v2[2 * p];
                        v3[p] = tk ? v2[2 * p + 1] : v2[2 * p];
                        i3[p] = tk ? i2[2 * p + 1] : i2[2 * p];
                    }
                    bool tk = v3[1] > v3[0];
                    float bv = tk ? v3[1] : v3[0];
                    int bi = tk ? i3[1] : i3[0];
                    float ov = __int_as_float(__builtin_amdgcn_ds_bpermute(addrx, __float_as_int(bv)));
                    int   oi = __builtin_amdgcn_ds_bpermute(addrx, bi);
                    bool take = (ov > bv) || (ov == bv && oi < bi);
                    if (take) { bv = ov; bi = oi; }
                    if (l < 32) bp[(t - 1) * KK + k] = (unsigned char)bi;
                    s = bv + pot;
                }
            }
        }
        // final first-index argmax over s
        float bv = s; int bi = k;
#pragma unroll
        for (int d = 16; d >= 1; d >>= 1) {
            float ov = __shfl_xor(bv, d, 64);
            int   oi = __shfl_xor(bi, d, 64);
            bool take = (ov > bv) || (ov == bv && oi < bi);
            if (take) { bv = ov; bi = oi; }
        }
        if (l == 0) last_tag_s = bi;
    } else {
        // ================= idle wave (barrier keep-up) =================
        for (int i = 0; i < TT + 2; ++i) __syncthreads();
    }
    __syncthreads();
    // ---- Phase A: chunk-parallel backtrack (12 groups over 32 chunks) ----
    {
        const int k = tid & 31;
        const int grp = tid >> 5;                      // 0..11
        for (int c = grp; c < 32; c += 12) {
            int tag = k;
            for (int ll = 31; ll >= 0; --ll) {
                const int t = c * 32 + ll;
                if (t < TT - 1) tag = bp[t * KK + tag];
                table[(c * 32 + ll) * KK + k] = (unsigned char)tag;
            }
        }
    }
    __syncthreads();
    if (tid == 0) {                                    // Phase B: stitch
        int e = last_tag_s;
        ent[31] = e;
        for (int c = 30; c >= 0; --c) { e = table[(c + 1) * 32 * KK + e]; ent[c] = e; }
    }
    __syncthreads();
    for (int t = tid; t < TT; t += 384) {              // Phase C: emit
        const int c = t >> 5, ll = t & 31;
        out_dec[(size_t)bTT + t] = (float)table[(c * 32 + ll) * KK + ent[c]];
    }
    if (b == 0) {
        for (int i2 = tid; i2 < KK * KK; i2 += 384) out_chn[i2] = chain[i2];
    }
}

// ---------------------------------------------------------------------------
extern "C" void kernel_launch(void* const* d_in, const int* in_sizes, int n_in,
                              void* d_out, int out_size, void* d_ws, size_t ws_size,
                              hipStream_t stream) {
    const float* X     = (const float*)d_in[0];
    const int*   mask  = (const int*)d_in[1];
    const float* Wk    = (const float*)d_in[2];   // [128,192]
    const float* Wr    = (const float*)d_in[3];   // [64,192]
    const float* gb    = (const float*)d_in[4];   // [2,192]
    const float* Dk    = (const float*)d_in[5];   // [64,32]
    const float* db    = (const float*)d_in[6];   // [32]
    const float* chain = (const float*)d_in[7];   // [32,32]
    const float* lb    = (const float*)d_in[8];
    const float* rb    = (const float*)d_in[9];

    float* out = (float*)d_out;
    float* out_dec  = out;                                   // [B,T]
    float* out_pot  = out + (size_t)BB * TT;                 // [B,T,K]
    float* out_slen = out + (size_t)BB * TT + (size_t)BB * TT * KK;        // [B]
    float* out_chn  = out_slen + BB;                         // [K,K]

    float* xp = (float*)d_ws;                                // [B*T,192]

    xproj_kernel<<<dim3((BB * TT) / 64, 3), dim3(256), 0, stream>>>(X, Wk, gb, xp);
    fused_kernel<<<dim3(BB), dim3(384), 0, stream>>>(xp, Wr, gb, mask, Dk, db, chain,
                                                     lb, rb, out_pot, out_dec,
                                                     out_slen, out_chn);
}

// Round 10
// 896.651 us; speedup vs baseline: 2.5913x; 1.0051x over previous
//
#include <hip/hip_runtime.h>
#include <math.h>

#define BB 128
#define TT 1024
#define DD 128
#define HH 64
#define G3 192   // 3*H
#define KK 32
#define CH 32    // staging chunk (steps)

// ---------------------------------------------------------------------------
// Kernel 1: xproj[B*T,192] = X[B*T,128] @ Wk[128,192] + b0  (unchanged)
// ---------------------------------------------------------------------------
__global__ __launch_bounds__(256, 2) void xproj_kernel(const float* __restrict__ X,
                                                       const float* __restrict__ Wk,
                                                       const float* __restrict__ gbias,
                                                       float* __restrict__ xp) {
    __shared__ float Xs[64 * 132];
    __shared__ float Ws[128 * 68];
    const int tid = threadIdx.x;
    const int row0 = blockIdx.x * 64;
    const int cg = blockIdx.y;
#pragma unroll
    for (int it = 0; it < 8; ++it) {
        int idx = it * 1024 + tid * 4;
        int r = idx >> 7, c = idx & 127;
        float4 v = *(const float4*)&X[((size_t)(row0 + r)) * DD + c];
        *(float4*)&Xs[r * 132 + c] = v;
    }
#pragma unroll
    for (int it = 0; it < 8; ++it) {
        int idx = it * 1024 + tid * 4;
        int k = idx >> 6, c = idx & 63;
        float4 v = *(const float4*)&Wk[(size_t)k * G3 + cg * 64 + c];
        *(float4*)&Ws[k * 68 + c] = v;
    }
    __syncthreads();
    const int tr = tid >> 4, tc = tid & 15;
    const int r0 = tr * 4, c0 = tc * 4;
    float acc[4][4];
#pragma unroll
    for (int r = 0; r < 4; ++r)
#pragma unroll
        for (int c = 0; c < 4; ++c) acc[r][c] = 0.f;
#pragma unroll 4
    for (int k = 0; k < DD; k += 4) {
        float a[4][4];
#pragma unroll
        for (int r = 0; r < 4; ++r) {
            float4 t = *(const float4*)&Xs[(r0 + r) * 132 + k];
            a[r][0] = t.x; a[r][1] = t.y; a[r][2] = t.z; a[r][3] = t.w;
        }
#pragma unroll
        for (int kk = 0; kk < 4; ++kk) {
            float4 b = *(const float4*)&Ws[(k + kk) * 68 + c0];
#pragma unroll
            for (int r = 0; r < 4; ++r) {
                acc[r][0] += a[r][kk] * b.x;
                acc[r][1] += a[r][kk] * b.y;
                acc[r][2] += a[r][kk] * b.z;
                acc[r][3] += a[r][kk] * b.w;
            }
        }
    }
    float4 bias = *(const float4*)&gbias[cg * 64 + c0];
#pragma unroll
    for (int r = 0; r < 4; ++r) {
        float4 o;
        o.x = acc[r][0] + bias.x; o.y = acc[r][1] + bias.y;
        o.z = acc[r][2] + bias.z; o.w = acc[r][3] + bias.w;
        *(float4*)&xp[((size_t)(row0 + r0 + r)) * G3 + cg * 64 + c0] = o;
    }
}

// ---------------------------------------------------------------------------
// Kernel 2: FUSED GRU + potentials + Viterbi, 5 waves, ZERO per-step global:
//   waves 0-2: GRU gates (weights asm-pinned in VGPRs; xv/mask from LDS)
//   wave 3:    pot matvec -> LDS ring  +  chunk staging (xp,mask in; pot out)
//   wave 4:    viterbi transition (pure LDS)
// Every per-step __syncthreads now drains nothing for waves 0-2,4 (no
// outstanding vmem) — the R9 stall was the compiler's vmcnt(0) drain of
// per-step global prefetch/stores at every barrier. Wave 3 pays one drain
// per 32-step chunk (amortized ~20cyc/step).
// Phase i: PRE | barrier | POST.  GRU h(t): POST(t). pot(t)=f(h(t)): PRE(t+2).
// vit consumes pot(t): POST(t+2). Stage chunk c+1 & flush pot chunk c-2 at
// PRE(32c). All waves run 1 + (TT+2) barriers before the backtrack phases.
// ---------------------------------------------------------------------------
#define BCAST(v, l) __int_as_float(__builtin_amdgcn_readlane(__float_as_int(v), (l)))

__global__ __launch_bounds__(320, 1)
void fused_kernel(const float* __restrict__ xp,
                  const float* __restrict__ Wr,
                  const float* __restrict__ gbias,
                  const int* __restrict__ mask,
                  const float* __restrict__ Dk,
                  const float* __restrict__ db,
                  const float* __restrict__ chain,
                  const float* __restrict__ lb,
                  const float* __restrict__ rb,
                  float* __restrict__ out_pot,
                  float* __restrict__ out_dec,
                  float* __restrict__ out_slen,
                  float* __restrict__ out_chn) {
    const int b = blockIdx.x;
    const int tid = threadIdx.x;
    const int w = tid >> 6;                    // 0..4
    const int l = tid & 63;
    const int bTT = b * TT;

    __shared__ unsigned char bp[(TT - 1) * KK];          // 32736 B
    __shared__ unsigned char table[32 * 32 * KK];        // 32768 B
    __shared__ int ent[32];
    __shared__ int last_tag_s;
    __shared__ float gbuf[2][4 * HH];                    // 2048 B
    __shared__ __align__(16) float hbuf[4][HH];          // 1024 B
    __shared__ __align__(16) float potring[64][KK];      // 8192 B
    __shared__ __align__(16) float xpstage[2][CH * G3];  // 49152 B
    __shared__ int maskst[2][CH];                        // 256 B

    if (w < 3) {
        // ================= GRU producer waves =================
        const int j = l;
        float wg[HH];
#pragma unroll
        for (int i2 = 0; i2 < HH; ++i2) wg[i2] = Wr[i2 * G3 + w * HH + j];
#pragma unroll
        for (int i2 = 0; i2 < HH; ++i2) asm volatile("" : "+v"(wg[i2]));
        const float bw = gbias[G3 + w * HH + j];
        __builtin_amdgcn_s_setprio(1);
        float h = 0.f;
        __syncthreads();                                  // pre-loop barrier
        float xv0 = xpstage[0][tid];                      // xv(0)
        int m0 = maskst[0][0];                            // m(0), broadcast
        for (int i = 0; i < TT + 2; ++i) {
            if (i < TT) {
                float a0 = bw, a1 = 0.f, a2 = 0.f, a3 = 0.f;
#pragma unroll
                for (int c = 0; c < HH; c += 4) {
                    a0 += BCAST(h, c + 0) * wg[c + 0];
                    a1 += BCAST(h, c + 1) * wg[c + 1];
                    a2 += BCAST(h, c + 2) * wg[c + 2];
                    a3 += BCAST(h, c + 3) * wg[c + 3];
                }
                float a = (a0 + a1) + (a2 + a3);
                float g = (w == 2) ? a : 1.f / (1.f + __expf(-(xv0 + a)));
                gbuf[i & 1][w * HH + j] = g;
                if (w == 2) gbuf[i & 1][3 * HH + j] = xv0;
            }
            __syncthreads();
            if (i < TT) {
                float z  = gbuf[i & 1][j];
                float r  = gbuf[i & 1][HH + j];
                float rh = gbuf[i & 1][2 * HH + j];
                float xh = gbuf[i & 1][3 * HH + j];
                float y = xh + r * rh;
                float hh = 1.f - 2.f / (1.f + __expf(2.f * y));   // tanh
                float hn = z * h + (1.f - z) * hh;
                hn = (m0 != 0) ? hn : h;
                h = hn;
                if (w == 0) hbuf[i & 3][j] = hn;
                if (i < TT - 1) {                        // prefetch step i+1
                    const int t1 = i + 1;
                    xv0 = xpstage[(t1 >> 5) & 1][(t1 & 31) * G3 + tid];
                    m0  = maskst[(t1 >> 5) & 1][t1 & 31];
                }
            }
        }
    } else if (w == 3) {
        // ============ pot matvec + chunk staging wave ============
        const int k = l & 31;
        int sl = 0;
#pragma unroll
        for (int q = 0; q < 16; ++q) sl += mask[bTT + q * 64 + l];
#pragma unroll
        for (int d = 32; d >= 1; d >>= 1) sl += __shfl_xor(sl, d, 64);
        if (l == 0) out_slen[b] = (float)sl;
        float dk[HH];
#pragma unroll
        for (int i2 = 0; i2 < HH; ++i2) dk[i2] = Dk[i2 * KK + k];
#pragma unroll
        for (int i2 = 0; i2 < HH; ++i2) asm volatile("" : "+v"(dk[i2]));
        const float dbk = db[k], lbk = lb[k], rbk = rb[k];
        const float* xpg = xp + (size_t)bTT * G3;
        float* potg = out_pot + (size_t)bTT * KK;
        // stage chunk 0
#pragma unroll
        for (int q = 0; q < 24; ++q) {
            float4 v = *(const float4*)&xpg[q * 256 + l * 4];
            *(float4*)&xpstage[0][q * 256 + l * 4] = v;
        }
        if (l < CH) maskst[0][l] = mask[bTT + l];
        __syncthreads();                                  // pre-loop barrier
        for (int i = 0; i < TT + 2; ++i) {
            if ((i & 31) == 0) {
                const int cn = (i >> 5) + 1;              // stage chunk cn
                if (cn < 32) {
                    const float* src = xpg + (size_t)cn * CH * G3;
                    float* dst = &xpstage[cn & 1][0];
#pragma unroll
                    for (int q = 0; q < 24; ++q) {
                        float4 v = *(const float4*)&src[q * 256 + l * 4];
                        *(float4*)&dst[q * 256 + l * 4] = v;
                    }
                    if (l < CH) maskst[cn & 1][l] = mask[bTT + cn * CH + l];
                }
                const int cf = (i >> 5) - 2;              // flush pot chunk cf
                if (cf >= 0) {
                    const float* srcl = &potring[(cf & 1) * 32][0];
                    float* dstg = potg + (size_t)cf * CH * KK;
#pragma unroll
                    for (int q = 0; q < 4; ++q) {
                        float4 v = *(const float4*)&srcl[q * 256 + l * 4];
                        *(float4*)&dstg[q * 256 + l * 4] = v;
                    }
                }
            }
            const int t = i - 2;
            if (t >= 0 && t < TT) {
                const float4* hv4 = (const float4*)&hbuf[t & 3][0];
                float p0 = dbk, p1 = 0.f, p2 = 0.f, p3 = 0.f;
#pragma unroll
                for (int c = 0; c < 16; ++c) {
                    float4 hv = hv4[c];
                    p0 += hv.x * dk[4 * c + 0];
                    p1 += hv.y * dk[4 * c + 1];
                    p2 += hv.z * dk[4 * c + 2];
                    p3 += hv.w * dk[4 * c + 3];
                }
                float pot = (p0 + p1) + (p2 + p3);
                if (t == 0) pot += lbk;
                if (t == sl - 1) pot += rbk;
                if (l < 32) potring[t & 63][k] = pot;
            }
            __syncthreads();
        }
        // flush last pot chunk (31)
        {
            const float* srcl = &potring[(31 & 1) * 32][0];
            float* dstg = potg + (size_t)31 * CH * KK;
#pragma unroll
            for (int q = 0; q < 4; ++q) {
                float4 v = *(const float4*)&srcl[q * 256 + l * 4];
                *(float4*)&dstg[q * 256 + l * 4] = v;
            }
        }
    } else {
        // ================= viterbi wave =================
        const int k = l & 31;
        const int hf = l >> 5;
        float ccol[16];
        int addr[16];
#pragma unroll
        for (int m = 0; m < 16; ++m) {
            ccol[m] = chain[(hf * 16 + m) * KK + k];
            addr[m] = (hf * 16 + m) * 4;
        }
#pragma unroll
        for (int m = 0; m < 16; ++m) asm volatile("" : "+v"(ccol[m]));
        const int addrx = (l ^ 32) * 4;
        float s = 0.f;
        __syncthreads();                                  // pre-loop barrier
        for (int i = 0; i < TT + 2; ++i) {
            __syncthreads();
            const int t = i - 2;
            if (t >= 0 && t < TT) {
                float pot = potring[t & 63][k];
                if (t == 0) {
                    s = pot;
                } else {
                    const int si = __float_as_int(s);
                    float c[16];
#pragma unroll
                    for (int m = 0; m < 16; ++m)
                        c[m] = __int_as_float(__builtin_amdgcn_ds_bpermute(addr[m], si)) + ccol[m];
                    float v1[8]; int i1[8];
#pragma unroll
                    for (int p = 0; p < 8; ++p) {
                        bool tk = c[2 * p + 1] > c[2 * p];
                        v1[p] = tk ? c[2 * p + 1] : c[2 * p];
                        i1[p] = hf * 16 + (tk ? 2 * p + 1 : 2 * p);
                    }
                    float v2[4]; int i2[4];
#pragma unroll
                    for (int p = 0; p < 4; ++p) {
                        bool tk = v1[2 * p + 1] > v1[2 * p];
                        v2[p] = tk ? v1[2 * p + 1] : v1[2 * p];
                        i2[p] = tk ? i1[2 * p + 1] : i1[2 * p];
                    }
                    float v3[2]; int i3[2];
#pragma unroll
                    for (int p = 0; p < 2; ++p) {
                        bool tk = v2[2 * p + 1] > v2[2 * p];
                        v3[p] = tk ? v2[2 * p + 1] : v2[2 * p];
                        i3[p] = tk ? i2[2 * p + 1] : i2[2 * p];
                    }
                    bool tk = v3[1] > v3[0];
                    float bv = tk ? v3[1] : v3[0];
                    int bi = tk ? i3[1] : i3[0];
                    float ov = __int_as_float(__builtin_amdgcn_ds_bpermute(addrx, __float_as_int(bv)));
                    int   oi = __builtin_amdgcn_ds_bpermute(addrx, bi);
                    bool take = (ov > bv) || (ov == bv && oi < bi);
                    if (take) { bv = ov; bi = oi; }
                    if (l < 32) bp[(t - 1) * KK + k] = (unsigned char)bi;
                    s = bv + pot;
                }
            }
        }
        float bv = s; int bi = k;
#pragma unroll
        for (int d = 16; d >= 1; d >>= 1) {
            float ov = __shfl_xor(bv, d, 64);
            int   oi = __shfl_xor(bi, d, 64);
            bool take = (ov > bv) || (ov == bv && oi < bi);
            if (take) { bv = ov; bi = oi; }
        }
        if (l == 0) last_tag_s = bi;
    }
    __syncthreads();
    // ---- Phase A: chunk-parallel backtrack (10 groups over 32 chunks) ----
    {
        const int k = tid & 31;
        const int grp = tid >> 5;                         // 0..9
        for (int c = grp; c < 32; c += 10) {
            int tag = k;
            for (int ll = 31; ll >= 0; --ll) {
                const int t = c * 32 + ll;
                if (t < TT - 1) tag = bp[t * KK + tag];
                table[(c * 32 + ll) * KK + k] = (unsigned char)tag;
            }
        }
    }
    __syncthreads();
    if (tid == 0) {                                       // Phase B: stitch
        int e = last_tag_s;
        ent[31] = e;
        for (int c = 30; c >= 0; --c) { e = table[(c + 1) * 32 * KK + e]; ent[c] = e; }
    }
    __syncthreads();
    for (int t = tid; t < TT; t += 320) {                 // Phase C: emit
        const int c = t >> 5, ll = t & 31;
        out_dec[(size_t)bTT + t] = (float)table[(c * 32 + ll) * KK + ent[c]];
    }
    if (b == 0) {
        for (int i2 = tid; i2 < KK * KK; i2 += 320) out_chn[i2] = chain[i2];
    }
}

// ---------------------------------------------------------------------------
extern "C" void kernel_launch(void* const* d_in, const int* in_sizes, int n_in,
                              void* d_out, int out_size, void* d_ws, size_t ws_size,
                              hipStream_t stream) {
    const float* X     = (const float*)d_in[0];
    const int*   mask  = (const int*)d_in[1];
    const float* Wk    = (const float*)d_in[2];   // [128,192]
    const float* Wr    = (const float*)d_in[3];   // [64,192]
    const float* gb    = (const float*)d_in[4];   // [2,192]
    const float* Dk    = (const float*)d_in[5];   // [64,32]
    const float* db    = (const float*)d_in[6];   // [32]
    const float* chain = (const float*)d_in[7];   // [32,32]
    const float* lb    = (const float*)d_in[8];
    const float* rb    = (const float*)d_in[9];

    float* out = (float*)d_out;
    float* out_dec  = out;                                   // [B,T]
    float* out_pot  = out + (size_t)BB * TT;                 // [B,T,K]
    float* out_slen = out + (size_t)BB * TT + (size_t)BB * TT * KK;        // [B]
    float* out_chn  = out_slen + BB;                         // [K,K]

    float* xp = (float*)d_ws;                                // [B*T,192]

    xproj_kernel<<<dim3((BB * TT) / 64, 3), dim3(256), 0, stream>>>(X, Wk, gb, xp);
    fused_kernel<<<dim3(BB), dim3(320), 0, stream>>>(xp, Wr, gb, mask, Dk, db, chain,
                                                     lb, rb, out_pot, out_dec,
                                                     out_slen, out_chn);
}